// Round 4
// baseline (243.251 us; speedup 1.0000x reference)
//
#include <hip/hip_runtime.h>

typedef unsigned int uint32;
typedef unsigned long long u64t;
typedef unsigned short u16t;
typedef uint32 v16u __attribute__((ext_vector_type(16)));

// ============================================================
// Compile-time reproduction of np.random.RandomState(0).randn
// (MT19937 + polar Box-Muller). Exact integer/IEEE-double control
// flow -> constexpr-safe; only log/sqrt evaluated on device.
// ============================================================
struct MTS { unsigned int mt[624]; int mti; };

constexpr unsigned int mt_next(MTS& s){
  if (s.mti >= 624){
    for (int i = 0; i < 624; i++){
      unsigned int y = (s.mt[i] & 0x80000000u) | (s.mt[(i+1)%624] & 0x7fffffffu);
      unsigned int v = s.mt[(i+397)%624] ^ (y >> 1);
      if (y & 1u) v ^= 2567483615u;
      s.mt[i] = v;
    }
    s.mti = 0;
  }
  unsigned int y = s.mt[s.mti]; s.mti++;
  y ^= y >> 11;
  y ^= (y << 7)  & 2636928640u;
  y ^= (y << 15) & 4022730752u;
  y ^= y >> 18;
  return y;
}
constexpr double mt_dbl(MTS& s){
  unsigned int a = mt_next(s) >> 5;
  unsigned int b = mt_next(s) >> 6;
  return ((double)a * 67108864.0 + (double)b) / 9007199254740992.0;
}

constexpr int NPAIR = 308;
struct GenData {
  double r2[NPAIR], x1[NPAIR], x2[NPAIR];
  int g_of_t[729];
};

constexpr GenData make_gen(){
  GenData g{};
  for (int i = 0; i < 729; i++) g.g_of_t[i] = -1;
  MTS s{};
  {
    unsigned int sd = 0u;
    for (int p = 0; p < 624; p++){
      s.mt[p] = sd;
      sd = 1812433253u * (sd ^ (sd >> 30)) + (unsigned)p + 1u;
    }
    s.mti = 624;
  }
  for (int p = 0; p < NPAIR; p++){
    double a = 0.0, b = 0.0, r = 0.0;
    do {
      a = 2.0 * mt_dbl(s) - 1.0;
      b = 2.0 * mt_dbl(s) - 1.0;
      r = a*a + b*b;
    } while (r >= 1.0 || r == 0.0);
    g.r2[p] = r; g.x1[p] = a; g.x2[p] = b;
  }
  const int L1[15] = {0,0,0,1,1,1,1,1,1,2,2,2,2,2,2};
  const int L2[15] = {0,1,2,0,1,1,1,2,2,0,1,1,2,2,2};
  const int L3[15] = {0,1,2,1,0,1,2,1,2,2,1,2,0,1,2};
  const int OFF[3] = {0,1,4};
  int gi = 0;
  for (int p = 0; p < 15; p++){
    int d1 = 2*L1[p]+1, d2 = 2*L2[p]+1, d3 = 2*L3[p]+1;
    for (int i = 0; i < d1; i++)
      for (int j = 0; j < d2; j++)
        for (int k = 0; k < d3; k++)
          g.g_of_t[(OFF[L1[p]]+i)*81 + (OFF[L2[p]]+j)*9 + (OFF[L3[p]]+k)] = gi++;
  }
  return g;
}

constexpr GenData h_gd = make_gen();
__constant__ GenData c_gd = h_gd;

__global__ void gen_T_kernel(float* __restrict__ T){
  int t = blockIdx.x * blockDim.x + threadIdx.x;
  if (t >= 729) return;
  int gi = c_gd.g_of_t[t];
  float v = 0.f;
  if (gi >= 0){
    int p = gi >> 1;
    double r2 = c_gd.r2[p];
    double f  = sqrt(-2.0 * log(r2) / r2);
    double xx = (gi & 1) ? c_gd.x1[p] : c_gd.x2[p];
    v = (float)((f * xx) / 3.0);
  }
  T[t] = v;
}

// ---- fp32 -> bf16 (RNE) ----
__device__ __forceinline__ u16t f2b(float f){
  uint32 u = __float_as_uint(f);
  u += 0x7fffu + ((u >> 16) & 1u);
  return (u16t)(u >> 16);
}

// x -> bf16, 4 elements per thread
__global__ __launch_bounds__(256) void x2b_kernel(const float* __restrict__ x,
                                                  u16t* __restrict__ xb, int n4){
  int i = blockIdx.x * 256 + threadIdx.x;
  if (i >= n4) return;
  const float4 v = *reinterpret_cast<const float4*>(x + (size_t)i * 4);
  uint32 a = (uint32)f2b(v.x) | ((uint32)f2b(v.y) << 16);
  uint32 b = (uint32)f2b(v.z) | ((uint32)f2b(v.w) << 16);
  reinterpret_cast<uint2*>(xb)[i] = make_uint2(a, b);
}

// ============================================================
// CSR-by-dst: hist -> scan -> fillW (computes W per slot, bf16)
// ============================================================
__global__ __launch_bounds__(256) void hist_kernel(const int* __restrict__ dst,
                                                   int* __restrict__ cnt,
                                                   int* __restrict__ pos, int E){
  int e = blockIdx.x * 256 + threadIdx.x;
  if (e < E) pos[e] = atomicAdd(&cnt[dst[e]], 1);
}

__global__ void scan_kernel(const int* __restrict__ cnt, int* __restrict__ start, int n){
  __shared__ int part[1024];
  int t = threadIdx.x;
  int ch = (n + 1023) >> 10;
  int b0 = t * ch;
  int sum = 0;
  for (int j = 0; j < ch; j++){ int i = b0 + j; if (i < n) sum += cnt[i]; }
  part[t] = sum;
  __syncthreads();
  for (int off = 1; off < 1024; off <<= 1){
    int v = 0;
    if (t >= off) v = part[t - off];
    __syncthreads();
    part[t] += v;
    __syncthreads();
  }
  int run = (t > 0) ? part[t-1] : 0;
  for (int j = 0; j < ch; j++){
    int i = b0 + j;
    if (i < n){ start[i] = run; run += cnt[i]; }
  }
  if (t == 1023) start[n] = part[1023];
}

// One wave per edge-group (16 edges): build W[81] = sh . T in lanes,
// store bf16 at CSR slot (96-ushort row = 192B), also esrc[p]=src.
__global__ __launch_bounds__(256) void fillW_kernel(
    const int* __restrict__ dst, const int* __restrict__ src,
    const float* __restrict__ sh, const int* __restrict__ start,
    const int* __restrict__ pos, const float* __restrict__ Tg,
    int* __restrict__ esrc, u16t* __restrict__ Wr, int E)
{
  const int wv = threadIdx.x >> 6;
  const int lane = threadIdx.x & 63;
  const int base = (blockIdx.x * 4 + wv) * 16;

  const int i0 = lane / 9, k0 = lane % 9;
  const bool has1 = (lane < 17);
  const int e1 = has1 ? (64 + lane) : 63;
  const int i1 = e1 / 9, k1 = e1 % 9;
  float t0[9], t1[9];
#pragma unroll
  for (int j = 0; j < 9; j++){
    t0[j] = Tg[i0*81 + j*9 + k0];
    t1[j] = Tg[i1*81 + j*9 + k1];
  }

  for (int ee = 0; ee < 16; ee++){
    const int e = base + ee;
    if (e >= E) return;
    const int p = start[dst[e]] + pos[e];
    if (lane == 0) esrc[p] = src[e];
    const float* s9 = sh + (size_t)e * 9;
    float sv[9];
#pragma unroll
    for (int j = 0; j < 9; j++) sv[j] = s9[j];
    float w0 = 0.f, w1 = 0.f;
#pragma unroll
    for (int j = 0; j < 9; j++){ w0 = fmaf(sv[j], t0[j], w0); w1 = fmaf(sv[j], t1[j], w1); }
    u16t* wrow = Wr + (size_t)p * 96;
    wrow[lane] = f2b(w0);
    if (has1) wrow[64 + lane] = f2b(w1);
  }
}

// ============================================================
// Main TP kernel: wave per node, lane = channel. W arrives via
// SCALAR loads (s_load_dwordx16 x3) -> SGPRs; unpack bf16 on the
// SALU; MACs are v_fmac v,s,v. x gathered as bf16 from SGPR base.
// ============================================================
__global__ __launch_bounds__(256) void tp_csr_sW(
    const u16t* __restrict__ xb, const int* __restrict__ esrc,
    const int* __restrict__ starts, const u16t* __restrict__ Wr,
    float* __restrict__ out, int n_nodes)
{
  const int wv = threadIdx.x >> 6;
  const int lane = threadIdx.x & 63;
  const int node = blockIdx.x * 4 + wv;
  if (node >= n_nodes) return;

  float acc[9];
#pragma unroll
  for (int k = 0; k < 9; k++) acc[k] = 0.f;

  const int s0 = __builtin_amdgcn_readfirstlane(starts[node]);
  const int s1 = __builtin_amdgcn_readfirstlane(starts[node + 1]);

  for (int idx = s0; idx < s1; ++idx){
    const int sn = __builtin_amdgcn_readfirstlane(esrc[idx]);
    const u16t* xr = xb + (size_t)sn * 576;

    // ---- x fragment (bf16 -> f32), SGPR base + per-lane offset
    float xv[9];
    xv[0] = __uint_as_float((uint32)xr[lane] << 16);
#pragma unroll
    for (int t = 0; t < 3; t++) xv[1 + t] = __uint_as_float((uint32)xr[64 + 3*lane + t] << 16);
#pragma unroll
    for (int t = 0; t < 5; t++) xv[4 + t] = __uint_as_float((uint32)xr[256 + 5*lane + t] << 16);

    // ---- W row via scalar loads (wave-uniform address)
    v16u A, B, C;
    u64t addr = (u64t)(const void*)(Wr + (size_t)idx * 96);
    asm volatile(
      "s_load_dwordx16 %0, %3, 0x0\n"
      "s_load_dwordx16 %1, %3, 0x40\n"
      "s_load_dwordx16 %2, %3, 0x80\n"
      "s_waitcnt lgkmcnt(0)"
      : "=s"(A), "=s"(B), "=s"(C) : "s"(addr));

    // ---- matvec: acc[k] += xv[i] * W[i*9+k], W unpacked on SALU
#pragma unroll
    for (int m = 0; m < 40; m++){
      const uint32 d = (m < 16) ? A[m] : ((m < 32) ? B[m - 16] : C[m - 32]);
      const int ta = 2*m, tb = 2*m + 1;
      acc[ta % 9] = fmaf(xv[ta / 9], __uint_as_float(d << 16), acc[ta % 9]);
      acc[tb % 9] = fmaf(xv[tb / 9], __uint_as_float(d & 0xffff0000u), acc[tb % 9]);
    }
    {
      const uint32 d = C[8];                 // t = 80 -> i=8, k=8
      acc[8] = fmaf(xv[8], __uint_as_float(d << 16), acc[8]);
    }
  }

  float* orow = out + (size_t)node * 576;
  orow[lane] = acc[0];
#pragma unroll
  for (int t = 0; t < 3; t++) orow[64 + 3*lane + t] = acc[1 + t];
#pragma unroll
  for (int t = 0; t < 5; t++) orow[256 + 5*lane + t] = acc[4 + t];
}

// ============================================================
// Mid fallback (R3 path): fill esrc+sh_r, readlane-broadcast tp
// ============================================================
__device__ __forceinline__ float bcast_lane(float v, int lane){
  return __uint_as_float(__builtin_amdgcn_readlane(__float_as_uint(v), lane));
}

__global__ __launch_bounds__(256) void fill_kernel(const int* __restrict__ dst,
                                                   const int* __restrict__ src,
                                                   const float* __restrict__ sh,
                                                   const int* __restrict__ start,
                                                   const int* __restrict__ pos,
                                                   int* __restrict__ esrc,
                                                   float* __restrict__ sh_r, int E){
  int e = blockIdx.x * 256 + threadIdx.x;
  if (e >= E) return;
  int p = start[dst[e]] + pos[e];
  esrc[p] = src[e];
  const float* s9 = sh + (size_t)e * 9;
  float* d9 = sh_r + (size_t)p * 9;
#pragma unroll
  for (int j = 0; j < 9; j++) d9[j] = s9[j];
}

__global__ __launch_bounds__(256) void tp_csr_rl(
    const float* __restrict__ x, const float* __restrict__ sh_r,
    const int* __restrict__ esrc, const int* __restrict__ starts,
    const float* __restrict__ Tg, float* __restrict__ out, int n_nodes)
{
  const int wv = threadIdx.x >> 6;
  const int lane = threadIdx.x & 63;
  const int node = blockIdx.x * 4 + wv;
  if (node >= n_nodes) return;

  const int i0 = lane / 9, k0 = lane % 9;
  const bool has1 = (lane < 17);
  const int e1 = has1 ? (64 + lane) : 63;
  const int i1 = e1 / 9, k1 = e1 % 9;
  float t0[9], t1[9];
#pragma unroll
  for (int j = 0; j < 9; j++){
    t0[j] = Tg[i0*81 + j*9 + k0];
    t1[j] = Tg[i1*81 + j*9 + k1];
  }

  float acc[9];
#pragma unroll
  for (int k = 0; k < 9; k++) acc[k] = 0.f;

  const int s0 = starts[node];
  const int s1 = starts[node + 1];

  for (int idx = s0; idx < s1; ++idx){
    const int sn = __builtin_amdgcn_readfirstlane(esrc[idx]);
    const float* xr = x + (size_t)sn * 576;
    float xv[9];
    xv[0] = xr[lane];
#pragma unroll
    for (int t = 0; t < 3; t++) xv[1 + t] = xr[64 + 3*lane + t];
#pragma unroll
    for (int t = 0; t < 5; t++) xv[4 + t] = xr[256 + 5*lane + t];

    const float* p9 = sh_r + (size_t)idx * 9;
    float sh_c[9];
#pragma unroll
    for (int j = 0; j < 9; j++) sh_c[j] = p9[j];

    float w0 = 0.f, w1 = 0.f;
#pragma unroll
    for (int j = 0; j < 9; j++) w0 = fmaf(sh_c[j], t0[j], w0);
#pragma unroll
    for (int j = 0; j < 9; j++) w1 = fmaf(sh_c[j], t1[j], w1);

#pragma unroll
    for (int i = 0; i < 9; i++){
      const float xi = xv[i];
#pragma unroll
      for (int k = 0; k < 9; k++){
        const int t = i*9 + k;
        const float w = (t < 64) ? bcast_lane(w0, t) : bcast_lane(w1, t - 64);
        acc[k] = fmaf(xi, w, acc[k]);
      }
    }
  }

  float* orow = out + (size_t)node * 576;
  orow[lane] = acc[0];
#pragma unroll
  for (int t = 0; t < 3; t++) orow[64 + 3*lane + t] = acc[1 + t];
#pragma unroll
  for (int t = 0; t < 5; t++) orow[256 + 5*lane + t] = acc[4 + t];
}

// ============================================================
// Last-resort fallback: edge-parallel with atomics
// ============================================================
__global__ __launch_bounds__(256) void tp_edge_atomic(
    const float* __restrict__ x, const float* __restrict__ sh,
    const int* __restrict__ src, const int* __restrict__ dst,
    const float* __restrict__ Tg, float* __restrict__ out, int E)
{
  const int wv = threadIdx.x >> 6;
  const int lane = threadIdx.x & 63;
  const int e = blockIdx.x * 4 + wv;
  if (e >= E) return;

  const int i0 = lane / 9, k0 = lane % 9;
  const bool has1 = (lane < 17);
  const int e1 = has1 ? (64 + lane) : 63;
  const int i1 = e1 / 9, k1 = e1 % 9;
  float t0[9], t1[9];
#pragma unroll
  for (int j = 0; j < 9; j++){
    t0[j] = Tg[i0*81 + j*9 + k0];
    t1[j] = Tg[i1*81 + j*9 + k1];
  }

  const int sn = src[e];
  const float* she = sh + (size_t)e * 9;
  float sv[9];
#pragma unroll
  for (int j = 0; j < 9; j++) sv[j] = she[j];

  float w0 = 0.f, w1 = 0.f;
#pragma unroll
  for (int j = 0; j < 9; j++) w0 = fmaf(sv[j], t0[j], w0);
#pragma unroll
  for (int j = 0; j < 9; j++) w1 = fmaf(sv[j], t1[j], w1);

  const float* xr = x + (size_t)sn * 576;
  float xv[9];
  xv[0] = xr[lane];
#pragma unroll
  for (int t = 0; t < 3; t++) xv[1 + t] = xr[64 + 3*lane + t];
#pragma unroll
  for (int t = 0; t < 5; t++) xv[4 + t] = xr[256 + 5*lane + t];

  float o[9];
#pragma unroll
  for (int k = 0; k < 9; k++) o[k] = 0.f;
#pragma unroll
  for (int i = 0; i < 9; i++){
    const float xi = xv[i];
#pragma unroll
    for (int k = 0; k < 9; k++){
      const int t = i*9 + k;
      const float w = (t < 64) ? bcast_lane(w0, t) : bcast_lane(w1, t - 64);
      o[k] = fmaf(xi, w, o[k]);
    }
  }

  float* orow = out + (size_t)dst[e] * 576;
  atomicAdd(&orow[lane], o[0]);
#pragma unroll
  for (int t = 0; t < 3; t++) atomicAdd(&orow[64 + 3*lane + t], o[1 + t]);
#pragma unroll
  for (int t = 0; t < 5; t++) atomicAdd(&orow[256 + 5*lane + t], o[4 + t]);
}

// ============================================================
extern "C" void kernel_launch(void* const* d_in, const int* in_sizes, int n_in,
                              void* d_out, int out_size, void* d_ws, size_t ws_size,
                              hipStream_t stream)
{
  const float* x  = (const float*)d_in[0];
  const float* sh = (const float*)d_in[1];
  const int* src  = (const int*)d_in[2];
  const int* dst  = (const int*)d_in[3];
  float* out = (float*)d_out;

  const int N = in_sizes[0] / 576;
  const int E = in_sizes[2];

  // layout (u32 units):
  // Tw[1024] | cnt[N] | strt[N+1] | pos[E] | esrc[E] | xb[288N] | Wr[48E]
  const size_t o_T    = 0;
  const size_t o_cnt  = 1024;
  const size_t o_strt = o_cnt + (size_t)N;
  const size_t o_pos  = o_strt + (size_t)N + 1;
  const size_t o_esrc = o_pos + (size_t)E;
  size_t o_xb   = o_esrc + (size_t)E;
  o_xb = (o_xb + 3) & ~(size_t)3;
  size_t o_Wr   = o_xb + (size_t)288 * N;
  o_Wr = (o_Wr + 15) & ~(size_t)15;            // 64B-align W rows
  const size_t need_big = (o_Wr + (size_t)48 * E) * 4;
  const size_t need_mid = ((size_t)1024 + N + (N + 1) + E + E + (size_t)9 * E) * 4;

  float* Tw = (float*)d_ws;
  gen_T_kernel<<<3, 256, 0, stream>>>(Tw);

  if (ws_size >= need_big){
    int* cnt    = (int*)d_ws + o_cnt;
    int* strt   = (int*)d_ws + o_strt;
    int* pos    = (int*)d_ws + o_pos;
    int* esrc   = (int*)d_ws + o_esrc;
    u16t* xb    = (u16t*)((uint32*)d_ws + o_xb);
    u16t* Wr    = (u16t*)((uint32*)d_ws + o_Wr);

    const int n4 = (int)(((size_t)N * 576) / 4);
    x2b_kernel<<<(n4 + 255) / 256, 256, 0, stream>>>(x, xb, n4);
    hipMemsetAsync(cnt, 0, (size_t)N * 4, stream);
    hist_kernel<<<(E + 255) / 256, 256, 0, stream>>>(dst, cnt, pos, E);
    scan_kernel<<<1, 1024, 0, stream>>>(cnt, strt, N);
    fillW_kernel<<<(E + 63) / 64, 256, 0, stream>>>(dst, src, sh, strt, pos, Tw, esrc, Wr, E);
    tp_csr_sW<<<(N + 3) / 4, 256, 0, stream>>>(xb, esrc, strt, Wr, out, N);
  } else if (ws_size >= need_mid){
    int* cnt    = (int*)d_ws + 1024;
    int* strt   = cnt + N;
    int* pos    = strt + N + 1;
    int* esrc   = pos + E;
    float* sh_r = (float*)(esrc + E);

    hipMemsetAsync(cnt, 0, (size_t)N * 4, stream);
    hist_kernel<<<(E + 255) / 256, 256, 0, stream>>>(dst, cnt, pos, E);
    scan_kernel<<<1, 1024, 0, stream>>>(cnt, strt, N);
    fill_kernel<<<(E + 255) / 256, 256, 0, stream>>>(dst, src, sh, strt, pos, esrc, sh_r, E);
    tp_csr_rl<<<(N + 3) / 4, 256, 0, stream>>>(x, sh_r, esrc, strt, Tw, out, N);
  } else {
    hipMemsetAsync(out, 0, (size_t)out_size * 4, stream);
    tp_edge_atomic<<<(E + 3) / 4, 256, 0, stream>>>(x, sh, src, dst, Tw, out, E);
  }
}